// Round 1
// baseline (757.315 us; speedup 1.0000x reference)
//
#include <hip/hip_runtime.h>
#include <hip/hip_bf16.h>
#include <math.h>

typedef __hip_bfloat16 bf16;

// Problem constants (derived defensively in kernel_launch where possible)
#define KIN 512
#define F1  256
#define F2  16
#define F3  40

// ---------------- CSR build ----------------

__global__ void k_zero(int* __restrict__ a, int n) {
  int i = blockIdx.x * 256 + threadIdx.x;
  if (i < n) a[i] = 0;
}

// Detect whether edge_index is int64 (little-endian: high words all zero) or int32.
__global__ void k_detect(const int* __restrict__ ei, int* __restrict__ flag) {
  if (threadIdx.x == 0 && blockIdx.x == 0) {
    *flag = (ei[1] == 0 && ei[3] == 0 && ei[5] == 0 && ei[7] == 0) ? 1 : 0;
  }
}

__global__ void k_count(const int* __restrict__ ei, const int* __restrict__ flag,
                        int* __restrict__ cnt, int E) {
  int e = blockIdx.x * 256 + threadIdx.x;
  if (e >= E) return;
  int is64 = *flag;
  int d = is64 ? ei[2 * E + 2 * e] : ei[E + e];
  atomicAdd(&cnt[d], 1);
}

__global__ void k_dinv(const int* __restrict__ cnt, float* __restrict__ dinv, int n) {
  int i = blockIdx.x * 256 + threadIdx.x;
  if (i < n) dinv[i] = rsqrtf((float)(cnt[i] + 1));  // +1 self-loop; deg>=1 always
}

__global__ __launch_bounds__(1024) void k_scan(const int* __restrict__ cnt,
                                               int* __restrict__ off, int n) {
  __shared__ int buf[1024];
  __shared__ int carry_s;
  if (threadIdx.x == 0) { carry_s = 0; off[0] = 0; }
  __syncthreads();
  for (int base = 0; base < n; base += 1024) {
    int i = base + threadIdx.x;
    int v = (i < n) ? cnt[i] : 0;
    buf[threadIdx.x] = v;
    __syncthreads();
    for (int d = 1; d < 1024; d <<= 1) {
      int t = (threadIdx.x >= d) ? buf[threadIdx.x - d] : 0;
      __syncthreads();
      buf[threadIdx.x] += t;
      __syncthreads();
    }
    if (i < n) off[i + 1] = carry_s + buf[threadIdx.x];
    __syncthreads();
    if (threadIdx.x == 0) carry_s += buf[1023];
    __syncthreads();
  }
}

__global__ void k_scatter(const int* __restrict__ ei, const int* __restrict__ flag,
                          const int* __restrict__ off, int* __restrict__ fill,
                          const float* __restrict__ dinv,
                          int* __restrict__ csrc, float* __restrict__ cw, int E) {
  int e = blockIdx.x * 256 + threadIdx.x;
  if (e >= E) return;
  int is64 = *flag;
  int s, d;
  if (is64) { s = ei[2 * e]; d = ei[2 * E + 2 * e]; }
  else      { s = ei[e];     d = ei[E + e]; }
  int pos = off[d] + atomicAdd(&fill[d], 1);
  csrc[pos] = s;
  cw[pos] = dinv[s] * dinv[d];
}

// ---------------- GEMM1: h1 = x @ W1  (f32 in, bf16 out) ----------------
// 64x64 tile, 256 threads, 4x4 microtile, K-step 16, A staged K-major.

__global__ __launch_bounds__(256) void k_gemm1(const float* __restrict__ A,  // [M,512]
                                               const float* __restrict__ B,  // [512,256]
                                               bf16* __restrict__ C,          // [M,256]
                                               int M) {
  __shared__ float As[16][64];   // [k][m]
  __shared__ float Bs[16][64];   // [k][n]
  const int K = KIN, NN = F1;
  int t  = threadIdx.x;
  int tx = t & 15, ty = t >> 4;           // n-group, m-group
  int row0 = blockIdx.x * 64, col0 = blockIdx.y * 64;
  float acc[4][4] = {};
  for (int k0 = 0; k0 < K; k0 += 16) {
    // stage A (transposed): thread t loads float4 of row m at k-offset
    {
      int m  = t >> 2;
      int kq = (t & 3) * 4;
      int gr = row0 + m;
      float4 v = make_float4(0.f, 0.f, 0.f, 0.f);
      if (gr < M) v = *(const float4*)(A + (size_t)gr * K + k0 + kq);
      As[kq + 0][m] = v.x; As[kq + 1][m] = v.y;
      As[kq + 2][m] = v.z; As[kq + 3][m] = v.w;
    }
    // stage B
    {
      int kk = t >> 4;
      int n4 = (t & 15) * 4;
      float4 v = *(const float4*)(B + (size_t)(k0 + kk) * NN + col0 + n4);
      *(float4*)&Bs[kk][n4] = v;
    }
    __syncthreads();
#pragma unroll
    for (int kk = 0; kk < 16; ++kk) {
      float4 a = *(const float4*)&As[kk][ty * 4];
      float4 b = *(const float4*)&Bs[kk][tx * 4];
      float av[4] = {a.x, a.y, a.z, a.w};
      float bv[4] = {b.x, b.y, b.z, b.w};
#pragma unroll
      for (int i = 0; i < 4; ++i)
#pragma unroll
        for (int j = 0; j < 4; ++j)
          acc[i][j] = fmaf(av[i], bv[j], acc[i][j]);
    }
    __syncthreads();
  }
#pragma unroll
  for (int i = 0; i < 4; ++i) {
    int r = row0 + ty * 4 + i;
    if (r < M) {
#pragma unroll
      for (int j = 0; j < 4; ++j)
        C[(size_t)r * NN + col0 + tx * 4 + j] = __float2bfloat16(acc[i][j]);
    }
  }
}

// ---------------- Aggregation, 256 features (layer 1) ----------------
// One block per dst node; thread t owns feature t. Gather from CSR.

__global__ __launch_bounds__(256) void k_agg1(const bf16* __restrict__ H,   // [N,256]
                                              const int* __restrict__ off,
                                              const int* __restrict__ csrc,
                                              const float* __restrict__ cw,
                                              const float* __restrict__ dinv,
                                              const float* __restrict__ bias,
                                              bf16* __restrict__ O, int N) {
  int i = blockIdx.x;
  int t = threadIdx.x;
  float di = dinv[i];
  float acc = di * di * __bfloat162float(H[(size_t)i * F1 + t]);
  int e1 = off[i + 1];
  for (int e = off[i]; e < e1; ++e) {
    int s = csrc[e];
    float w = cw[e];
    acc = fmaf(w, __bfloat162float(H[(size_t)s * F1 + t]), acc);
  }
  float v = acc + bias[t];
  O[(size_t)i * F1 + t] = __float2bfloat16(fmaxf(v, 0.f));
}

// ---------------- GEMM2: h2 = out1 @ W2  (bf16 in, f32 out) ----------------
// Block: 16 rows x 16 cols, 256 threads, one output each; tiles in LDS.

__global__ __launch_bounds__(256) void k_gemm2(const bf16* __restrict__ A,  // [N,256]
                                               const float* __restrict__ W, // [256,16]
                                               float* __restrict__ C, int N) {
  __shared__ float Ws[F1 * F2];      // 16 KB
  __shared__ float Ts[16][F1];       // 16 KB
  int t  = threadIdx.x;
  int r0 = blockIdx.x * 16;
#pragma unroll
  for (int j = 0; j < 16; ++j) Ws[t + 256 * j] = W[t + 256 * j];
#pragma unroll
  for (int j = 0; j < 16; ++j) {
    int idx = t + 256 * j;
    int r = idx >> 8, k = idx & 255;
    int row = r0 + r;
    Ts[r][k] = (row < N) ? __bfloat162float(A[(size_t)row * F1 + k]) : 0.f;
  }
  __syncthreads();
  int r = t >> 4, c = t & 15;
  float acc = 0.f;
  const float4* tv = (const float4*)&Ts[r][0];
#pragma unroll 8
  for (int k4 = 0; k4 < 64; ++k4) {
    float4 a = tv[k4];
    int k = k4 * 4;
    acc = fmaf(a.x, Ws[(k + 0) * 16 + c], acc);
    acc = fmaf(a.y, Ws[(k + 1) * 16 + c], acc);
    acc = fmaf(a.z, Ws[(k + 2) * 16 + c], acc);
    acc = fmaf(a.w, Ws[(k + 3) * 16 + c], acc);
  }
  int row = r0 + r;
  if (row < N) C[(size_t)row * F2 + c] = acc;
}

// ---------------- Aggregation, 16 features (layers 2 & 3) ----------------
// 16 nodes per 256-thread block; 16 threads per node.

__global__ __launch_bounds__(256) void k_agg16(const float* __restrict__ H,  // [N,16]
                                               const int* __restrict__ off,
                                               const int* __restrict__ csrc,
                                               const float* __restrict__ cw,
                                               const float* __restrict__ dinv,
                                               const float* __restrict__ bias,
                                               float* __restrict__ O, int N, int relu) {
  int t = threadIdx.x;
  int i = blockIdx.x * 16 + (t >> 4);
  int f = t & 15;
  if (i >= N) return;
  float di = dinv[i];
  float acc = di * di * H[(size_t)i * F2 + f];
  int e1 = off[i + 1];
  for (int e = off[i]; e < e1; ++e)
    acc = fmaf(cw[e], H[(size_t)csrc[e] * F2 + f], acc);
  if (bias) acc += bias[f];
  if (relu) acc = fmaxf(acc, 0.f);
  O[(size_t)i * F2 + f] = acc;
}

// ---------------- GEMM3 + bias + log_softmax (fused) ----------------
// One wave per row (4 rows / 256-thread block). Lane c<40 owns column c.

__global__ __launch_bounds__(256) void k_gemm3_lsm(const float* __restrict__ A, // [N,16]
                                                   const float* __restrict__ W, // [16,40]
                                                   const float* __restrict__ b, // [40]
                                                   float* __restrict__ O, int N) {
  __shared__ float Ws[F2 * F3];  // 640
  __shared__ float bs[F3];
  int t = threadIdx.x;
  for (int idx = t; idx < F2 * F3; idx += 256) Ws[idx] = W[idx];
  if (t < F3) bs[t] = b[t];
  __syncthreads();
  int lane = t & 63;
  int wv   = t >> 6;
  int row  = blockIdx.x * 4 + wv;
  if (row >= N) return;
  const float* ar = A + (size_t)row * F2;
  int c = lane;
  float o = -INFINITY;
  if (c < F3) {
    float acc = bs[c];
#pragma unroll
    for (int k = 0; k < F2; ++k) acc = fmaf(ar[k], Ws[k * F3 + c], acc);
    o = acc;
  }
  float m = o;
  for (int d = 32; d; d >>= 1) m = fmaxf(m, __shfl_xor(m, d, 64));
  float ex = (c < F3) ? expf(o - m) : 0.f;
  float s = ex;
  for (int d = 32; d; d >>= 1) s += __shfl_xor(s, d, 64);
  float lse = m + logf(s);
  if (c < F3) O[(size_t)row * F3 + c] = o - lse;
}

// ---------------- launch ----------------

extern "C" void kernel_launch(void* const* d_in, const int* in_sizes, int n_in,
                              void* d_out, int out_size, void* d_ws, size_t ws_size,
                              hipStream_t stream) {
  const float* x  = (const float*)d_in[0];
  const int*   ei = (const int*)d_in[1];
  const float* W1 = (const float*)d_in[2];
  const float* b1 = (const float*)d_in[3];
  const float* W2 = (const float*)d_in[4];
  const float* b2 = (const float*)d_in[5];
  const float* W3 = (const float*)d_in[6];
  const float* b3 = (const float*)d_in[7];
  float* out = (float*)d_out;

  int N = in_sizes[0] / KIN;   // 50000
  int E = in_sizes[1] / 2;     // 800000

  char* p = (char*)d_ws;
  auto take = [&](size_t bytes) {
    char* r = p;
    p += (bytes + 255) & ~(size_t)255;
    return r;
  };
  int*   flag = (int*)take(4);
  int*   cnt  = (int*)take((size_t)N * 4);
  int*   fill = (int*)take((size_t)N * 4);
  int*   off  = (int*)take((size_t)(N + 1) * 4);
  float* dinv = (float*)take((size_t)N * 4);
  int*   csrc = (int*)take((size_t)E * 4);
  float* cw   = (float*)take((size_t)E * 4);
  bf16*  h1   = (bf16*)take((size_t)N * F1 * 2);
  bf16*  out1 = (bf16*)take((size_t)N * F1 * 2);
  float* h2   = (float*)take((size_t)N * F2 * 4);
  float* out2 = (float*)take((size_t)N * F2 * 4);
  float* agg3 = (float*)take((size_t)N * F2 * 4);

  int nb  = (N + 255) / 256;
  int ebk = (E + 255) / 256;

  k_detect<<<1, 64, 0, stream>>>(ei, flag);
  k_zero<<<nb, 256, 0, stream>>>(cnt, N);
  k_zero<<<nb, 256, 0, stream>>>(fill, N);
  k_count<<<ebk, 256, 0, stream>>>(ei, flag, cnt, E);
  k_dinv<<<nb, 256, 0, stream>>>(cnt, dinv, N);
  k_scan<<<1, 1024, 0, stream>>>(cnt, off, N);
  k_scatter<<<ebk, 256, 0, stream>>>(ei, flag, off, fill, dinv, csrc, cw, E);

  dim3 g1((N + 63) / 64, F1 / 64);
  k_gemm1<<<g1, 256, 0, stream>>>(x, W1, h1, N);
  k_agg1<<<N, 256, 0, stream>>>(h1, off, csrc, cw, dinv, b1, out1, N);

  k_gemm2<<<(N + 15) / 16, 256, 0, stream>>>(out1, W2, h2, N);
  k_agg16<<<(N + 15) / 16, 256, 0, stream>>>(h2, off, csrc, cw, dinv, b2, out2, N, 1);
  k_agg16<<<(N + 15) / 16, 256, 0, stream>>>(out2, off, csrc, cw, dinv, nullptr, agg3, N, 0);
  k_gemm3_lsm<<<(N + 3) / 4, 256, 0, stream>>>(agg3, W3, b3, out, N);
}

// Round 2
// 460.953 us; speedup vs baseline: 1.6429x; 1.6429x over previous
//
#include <hip/hip_runtime.h>
#include <hip/hip_bf16.h>
#include <math.h>

typedef __hip_bfloat16 bf16;
typedef __attribute__((ext_vector_type(8))) __bf16 bf16x8;
typedef __attribute__((ext_vector_type(4))) float f32x4;

#define KIN 512
#define F1  256
#define F2  16
#define F3  40

// ---------------- helpers ----------------

__device__ inline unsigned pk_bf2(float a, float b) {
  bf16 x = __float2bfloat16(a), y = __float2bfloat16(b);
  unsigned short ux = *(unsigned short*)&x, uy = *(unsigned short*)&y;
  return (unsigned)ux | ((unsigned)uy << 16);
}
__device__ inline float bfbits(unsigned u16) {
  unsigned v = u16 << 16;
  return *(float*)&v;
}
__device__ inline void async16(const void* g, void* l) {
  __builtin_amdgcn_global_load_lds((const __attribute__((address_space(1))) void*)g,
                                   (__attribute__((address_space(3))) void*)l, 16, 0, 0);
}

// ---------------- CSR build ----------------

__global__ void k_zero(int* __restrict__ a, int n) {
  int i = blockIdx.x * 256 + threadIdx.x;
  if (i < n) a[i] = 0;
}

__global__ void k_detect(const int* __restrict__ ei, int* __restrict__ flag) {
  if (threadIdx.x == 0 && blockIdx.x == 0)
    *flag = (ei[1] == 0 && ei[3] == 0 && ei[5] == 0 && ei[7] == 0) ? 1 : 0;
}

__global__ void k_count(const int* __restrict__ ei, const int* __restrict__ flag,
                        int* __restrict__ cnt, int E) {
  int e = blockIdx.x * 256 + threadIdx.x;
  if (e >= E) return;
  int is64 = *flag;
  int d = is64 ? ei[2 * E + 2 * e] : ei[E + e];
  atomicAdd(&cnt[d], 1);
}

__global__ void k_dinv(const int* __restrict__ cnt, float* __restrict__ dinv, int n) {
  int i = blockIdx.x * 256 + threadIdx.x;
  if (i < n) dinv[i] = rsqrtf((float)(cnt[i] + 1));
}

// 3-pass scan: per-1024-chunk scan -> scan of 49 partials -> add carries
__global__ __launch_bounds__(256) void k_scan1(const int* __restrict__ cnt,
                                               int* __restrict__ off,
                                               int* __restrict__ bsum, int N) {
  __shared__ int s[256];
  int t = threadIdx.x;
  int base = blockIdx.x * 1024 + t * 4;
  int v0 = (base + 0 < N) ? cnt[base + 0] : 0;
  int v1 = (base + 1 < N) ? cnt[base + 1] : 0;
  int v2 = (base + 2 < N) ? cnt[base + 2] : 0;
  int v3 = (base + 3 < N) ? cnt[base + 3] : 0;
  int tsum = v0 + v1 + v2 + v3;
  s[t] = tsum;
  __syncthreads();
  for (int d = 1; d < 256; d <<= 1) {
    int u = (t >= d) ? s[t - d] : 0;
    __syncthreads();
    s[t] += u;
    __syncthreads();
  }
  int excl = s[t] - tsum;
  int p0 = excl + v0, p1 = p0 + v1, p2 = p1 + v2, p3 = p2 + v3;
  if (base + 0 < N) off[base + 1] = p0;
  if (base + 1 < N) off[base + 2] = p1;
  if (base + 2 < N) off[base + 3] = p2;
  if (base + 3 < N) off[base + 4] = p3;
  if (t == 255) bsum[blockIdx.x] = s[255];
}

__global__ void k_scan2(const int* __restrict__ bsum, int* __restrict__ carry, int nb) {
  int t = threadIdx.x;
  int v = (t < nb) ? bsum[t] : 0;
  int incl = v;
  for (int d = 1; d < 64; d <<= 1) {
    int u = __shfl_up(incl, d, 64);
    if (t >= d) incl += u;
  }
  if (t < nb) carry[t] = incl - v;
}

__global__ __launch_bounds__(256) void k_scan3(int* __restrict__ off,
                                               const int* __restrict__ carry, int N) {
  int t = threadIdx.x;
  int c = carry[blockIdx.x];
  int base = blockIdx.x * 1024 + t * 4;
#pragma unroll
  for (int k = 0; k < 4; ++k)
    if (base + k < N) off[base + k + 1] += c;
  if (blockIdx.x == 0 && t == 0) off[0] = 0;
}

__global__ void k_scatter(const int* __restrict__ ei, const int* __restrict__ flag,
                          const int* __restrict__ off, int* __restrict__ fill,
                          const float* __restrict__ dinv,
                          int* __restrict__ csrc, float* __restrict__ cw, int E) {
  int e = blockIdx.x * 256 + threadIdx.x;
  if (e >= E) return;
  int is64 = *flag;
  int s, d;
  if (is64) { s = ei[2 * e]; d = ei[2 * E + 2 * e]; }
  else      { s = ei[e];     d = ei[E + e]; }
  int pos = off[d] + atomicAdd(&fill[d], 1);
  csrc[pos] = s;
  cw[pos] = dinv[s] * dinv[d];
}

// ---------------- W1 transpose+convert: W1t[n][k] bf16 ----------------
__global__ __launch_bounds__(256) void k_prep_w1(const float* __restrict__ W,
                                                 unsigned short* __restrict__ Wt) {
  int idx = blockIdx.x * 256 + threadIdx.x;   // idx = n*512 + k
  int n = idx >> 9, k = idx & 511;
  bf16 v = __float2bfloat16(W[(size_t)k * F1 + n]);
  Wt[idx] = *(unsigned short*)&v;
}

// ---------------- GEMM1: h1 = bf16(x) @ W1 via MFMA ----------------
// Tile 64(M) x 256(N), BK=32, 256 threads (4 waves), wave w -> cols [w*64, w*64+64).
// A staged f32->bf16 via ds_write (XOR chunk swizzle); B staged via global_load_lds.

__global__ __launch_bounds__(256) void k_gemm1(const float* __restrict__ A,       // [M,512] f32
                                               const unsigned short* __restrict__ Bt, // [256,512] bf16
                                               bf16* __restrict__ C,               // [M,256]
                                               int M) {
  __shared__ unsigned short As[64 * 32];    // [m][chunk-swizzled k], 4 KB
  __shared__ unsigned short Bs[256 * 32];   // [n][chunk-swizzled k], 16 KB
  int t = threadIdx.x;
  int wave = t >> 6, lane = t & 63;
  int row0 = blockIdx.x * 64;

  f32x4 acc[4][4];
#pragma unroll
  for (int i = 0; i < 4; ++i)
#pragma unroll
    for (int j = 0; j < 4; ++j) acc[i][j] = {0.f, 0.f, 0.f, 0.f};

  // staging coords
  int arow = t >> 2;            // 0..63
  int achk = t & 3;             // logical k-chunk
  int ar = row0 + arow; if (ar >= M) ar = M - 1;
  const float* ag = A + (size_t)ar * KIN + achk * 8;
  unsigned short* aw = As + arow * 32 + (achk ^ ((arow >> 1) & 3)) * 8;

  int brow_l = lane >> 2;       // 0..15 within issue
  int bchk_p = lane & 3;        // physical chunk this lane fills

  for (int k0 = 0; k0 < KIN; k0 += 32) {
    __syncthreads();  // previous compute done reading LDS
    // stage A: load 8 f32, convert, ds_write_b128
    {
      float4 f0 = *(const float4*)(ag + k0);
      float4 f1 = *(const float4*)(ag + k0 + 4);
      uint4 pk;
      pk.x = pk_bf2(f0.x, f0.y); pk.y = pk_bf2(f0.z, f0.w);
      pk.z = pk_bf2(f1.x, f1.y); pk.w = pk_bf2(f1.z, f1.w);
      *(uint4*)aw = pk;
    }
    // stage B: 4 issues of 16 rows per wave, global_load_lds 16B
#pragma unroll
    for (int j = 0; j < 4; ++j) {
      int nr = wave * 64 + j * 16;
      int row = nr + brow_l;
      int gchk = bchk_p ^ ((row >> 1) & 3);
      const unsigned short* gp = Bt + (size_t)row * KIN + k0 + gchk * 8;
      async16(gp, Bs + nr * 32);   // lds = base + lane*16
    }
    __syncthreads();  // staging visible
    // compute: 16 MFMA
    int q = lane >> 4, m16 = lane & 15;
    bf16x8 a[4];
#pragma unroll
    for (int i = 0; i < 4; ++i) {
      int m = i * 16 + m16;
      a[i] = *(const bf16x8*)(As + m * 32 + ((q ^ ((m >> 1) & 3)) * 8));
    }
#pragma unroll
    for (int j = 0; j < 4; ++j) {
      int n = wave * 64 + j * 16 + m16;
      bf16x8 b = *(const bf16x8*)(Bs + n * 32 + ((q ^ ((n >> 1) & 3)) * 8));
#pragma unroll
      for (int i = 0; i < 4; ++i)
        acc[i][j] = __builtin_amdgcn_mfma_f32_16x16x32_bf16(a[i], b, acc[i][j], 0, 0, 0);
    }
  }
  // epilogue: D[row=(lane>>4)*4+r][col=lane&15] per 16x16 tile
  int q = lane >> 4, c16 = lane & 15;
#pragma unroll
  for (int i = 0; i < 4; ++i) {
#pragma unroll
    for (int r = 0; r < 4; ++r) {
      int row = row0 + i * 16 + q * 4 + r;
      if (row < M) {
#pragma unroll
        for (int j = 0; j < 4; ++j) {
          int col = wave * 64 + j * 16 + c16;
          C[(size_t)row * F1 + col] = __float2bfloat16(acc[i][j][r]);
        }
      }
    }
  }
}

// ---------------- Aggregation, 256 features (layer 1) ----------------
// 8 nodes/block, 32 lanes/node, each lane owns 8 features (16B loads).

__global__ __launch_bounds__(256) void k_agg1(const bf16* __restrict__ H,
                                              const int* __restrict__ off,
                                              const int* __restrict__ csrc,
                                              const float* __restrict__ cw,
                                              const float* __restrict__ dinv,
                                              const float* __restrict__ bias,
                                              bf16* __restrict__ O, int N) {
  int t = threadIdx.x;
  int i = blockIdx.x * 8 + (t >> 5);
  if (i >= N) return;
  int f0 = (t & 31) * 8;
  const unsigned short* Hu = (const unsigned short*)H;
  float di = dinv[i];
  float w0 = di * di;
  float acc[8];
  {
    uint4 h = *(const uint4*)(Hu + (size_t)i * F1 + f0);
    acc[0] = w0 * bfbits(h.x & 0xffff); acc[1] = w0 * bfbits(h.x >> 16);
    acc[2] = w0 * bfbits(h.y & 0xffff); acc[3] = w0 * bfbits(h.y >> 16);
    acc[4] = w0 * bfbits(h.z & 0xffff); acc[5] = w0 * bfbits(h.z >> 16);
    acc[6] = w0 * bfbits(h.w & 0xffff); acc[7] = w0 * bfbits(h.w >> 16);
  }
  int e1 = off[i + 1];
  for (int e = off[i]; e < e1; ++e) {
    int s = csrc[e];
    float w = cw[e];
    uint4 h = *(const uint4*)(Hu + (size_t)s * F1 + f0);
    acc[0] = fmaf(w, bfbits(h.x & 0xffff), acc[0]);
    acc[1] = fmaf(w, bfbits(h.x >> 16),    acc[1]);
    acc[2] = fmaf(w, bfbits(h.y & 0xffff), acc[2]);
    acc[3] = fmaf(w, bfbits(h.y >> 16),    acc[3]);
    acc[4] = fmaf(w, bfbits(h.z & 0xffff), acc[4]);
    acc[5] = fmaf(w, bfbits(h.z >> 16),    acc[5]);
    acc[6] = fmaf(w, bfbits(h.w & 0xffff), acc[6]);
    acc[7] = fmaf(w, bfbits(h.w >> 16),    acc[7]);
  }
  float4 b0 = *(const float4*)(bias + f0);
  float4 b1 = *(const float4*)(bias + f0 + 4);
  float bb[8] = {b0.x, b0.y, b0.z, b0.w, b1.x, b1.y, b1.z, b1.w};
  uint4 o;
  unsigned* op = (unsigned*)&o;
#pragma unroll
  for (int k = 0; k < 4; ++k) {
    float lo = fmaxf(acc[2 * k] + bb[2 * k], 0.f);
    float hi = fmaxf(acc[2 * k + 1] + bb[2 * k + 1], 0.f);
    op[k] = pk_bf2(lo, hi);
  }
  *(uint4*)((unsigned short*)O + (size_t)i * F1 + f0) = o;
}

// ---------------- GEMM2: h2 = out1 @ W2 (bf16 in, f32 out) ----------------

__global__ __launch_bounds__(256) void k_gemm2(const bf16* __restrict__ A,
                                               const float* __restrict__ W,
                                               float* __restrict__ C, int N) {
  __shared__ float Ws[F1 * F2];
  __shared__ float Ts[16][F1];
  int t = threadIdx.x;
  int r0 = blockIdx.x * 16;
#pragma unroll
  for (int j = 0; j < 16; ++j) Ws[t + 256 * j] = W[t + 256 * j];
#pragma unroll
  for (int j = 0; j < 16; ++j) {
    int idx = t + 256 * j;
    int r = idx >> 8, k = idx & 255;
    int row = r0 + r;
    Ts[r][k] = (row < N) ? __bfloat162float(A[(size_t)row * F1 + k]) : 0.f;
  }
  __syncthreads();
  int r = t >> 4, c = t & 15;
  float acc = 0.f;
  const float4* tv = (const float4*)&Ts[r][0];
#pragma unroll 8
  for (int k4 = 0; k4 < 64; ++k4) {
    float4 a = tv[k4];
    int k = k4 * 4;
    acc = fmaf(a.x, Ws[(k + 0) * 16 + c], acc);
    acc = fmaf(a.y, Ws[(k + 1) * 16 + c], acc);
    acc = fmaf(a.z, Ws[(k + 2) * 16 + c], acc);
    acc = fmaf(a.w, Ws[(k + 3) * 16 + c], acc);
  }
  int row = r0 + r;
  if (row < N) C[(size_t)row * F2 + c] = acc;
}

// ---------------- Aggregation, 16 features ----------------

__global__ __launch_bounds__(256) void k_agg16(const float* __restrict__ H,
                                               const int* __restrict__ off,
                                               const int* __restrict__ csrc,
                                               const float* __restrict__ cw,
                                               const float* __restrict__ dinv,
                                               const float* __restrict__ bias,
                                               float* __restrict__ O, int N, int relu) {
  int t = threadIdx.x;
  int i = blockIdx.x * 16 + (t >> 4);
  int f = t & 15;
  if (i >= N) return;
  float di = dinv[i];
  float acc = di * di * H[(size_t)i * F2 + f];
  int e1 = off[i + 1];
  for (int e = off[i]; e < e1; ++e)
    acc = fmaf(cw[e], H[(size_t)csrc[e] * F2 + f], acc);
  if (bias) acc += bias[f];
  if (relu) acc = fmaxf(acc, 0.f);
  O[(size_t)i * F2 + f] = acc;
}

// ---------------- GEMM3 + bias + log_softmax ----------------

__global__ __launch_bounds__(256) void k_gemm3_lsm(const float* __restrict__ A,
                                                   const float* __restrict__ W,
                                                   const float* __restrict__ b,
                                                   float* __restrict__ O, int N) {
  __shared__ float Ws[F2 * F3];
  __shared__ float bs[F3];
  int t = threadIdx.x;
  for (int idx = t; idx < F2 * F3; idx += 256) Ws[idx] = W[idx];
  if (t < F3) bs[t] = b[t];
  __syncthreads();
  int lane = t & 63;
  int wv = t >> 6;
  int row = blockIdx.x * 4 + wv;
  if (row >= N) return;
  const float* ar = A + (size_t)row * F2;
  int c = lane;
  float o = -INFINITY;
  if (c < F3) {
    float acc = bs[c];
#pragma unroll
    for (int k = 0; k < F2; ++k) acc = fmaf(ar[k], Ws[k * F3 + c], acc);
    o = acc;
  }
  float m = o;
  for (int d = 32; d; d >>= 1) m = fmaxf(m, __shfl_xor(m, d, 64));
  float ex = (c < F3) ? expf(o - m) : 0.f;
  float s = ex;
  for (int d = 32; d; d >>= 1) s += __shfl_xor(s, d, 64);
  float lse = m + logf(s);
  if (c < F3) O[(size_t)row * F3 + c] = o - lse;
}

// ---------------- launch ----------------

extern "C" void kernel_launch(void* const* d_in, const int* in_sizes, int n_in,
                              void* d_out, int out_size, void* d_ws, size_t ws_size,
                              hipStream_t stream) {
  const float* x  = (const float*)d_in[0];
  const int*   ei = (const int*)d_in[1];
  const float* W1 = (const float*)d_in[2];
  const float* b1 = (const float*)d_in[3];
  const float* W2 = (const float*)d_in[4];
  const float* b2 = (const float*)d_in[5];
  const float* W3 = (const float*)d_in[6];
  const float* b3 = (const float*)d_in[7];
  float* out = (float*)d_out;

  int N = in_sizes[0] / KIN;
  int E = in_sizes[1] / 2;

  char* p = (char*)d_ws;
  auto take = [&](size_t bytes) {
    char* r = p;
    p += (bytes + 255) & ~(size_t)255;
    return r;
  };
  int*   flag  = (int*)take(4);
  int*   cnt   = (int*)take((size_t)N * 4);
  int*   fill  = (int*)take((size_t)N * 4);
  int*   off   = (int*)take((size_t)(N + 1) * 4);
  float* dinv  = (float*)take((size_t)N * 4);
  int*   bsum  = (int*)take(64 * 4);
  int*   carry = (int*)take(64 * 4);
  int*   csrc  = (int*)take((size_t)E * 4);
  float* cw    = (float*)take((size_t)E * 4);
  unsigned short* w1t = (unsigned short*)take((size_t)KIN * F1 * 2);
  bf16*  h1    = (bf16*)take((size_t)N * F1 * 2);
  bf16*  out1  = (bf16*)take((size_t)N * F1 * 2);
  float* h2    = (float*)take((size_t)N * F2 * 4);
  float* out2  = (float*)take((size_t)N * F2 * 4);
  float* agg3  = (float*)take((size_t)N * F2 * 4);

  int nb   = (N + 255) / 256;
  int ebk  = (E + 255) / 256;
  int nsc  = (N + 1023) / 1024;

  k_detect<<<1, 64, 0, stream>>>(ei, flag);
  k_zero<<<nb, 256, 0, stream>>>(cnt, N);
  k_zero<<<nb, 256, 0, stream>>>(fill, N);
  k_count<<<ebk, 256, 0, stream>>>(ei, flag, cnt, E);
  k_dinv<<<nb, 256, 0, stream>>>(cnt, dinv, N);
  k_scan1<<<nsc, 256, 0, stream>>>(cnt, off, bsum, N);
  k_scan2<<<1, 64, 0, stream>>>(bsum, carry, nsc);
  k_scan3<<<nsc, 256, 0, stream>>>(off, carry, N);
  k_scatter<<<ebk, 256, 0, stream>>>(ei, flag, off, fill, dinv, csrc, cw, E);

  k_prep_w1<<<(KIN * F1) / 256, 256, 0, stream>>>(W1, w1t);
  k_gemm1<<<(N + 63) / 64, 256, 0, stream>>>(x, w1t, h1, N);
  k_agg1<<<(N + 7) / 8, 256, 0, stream>>>(h1, off, csrc, cw, dinv, b1, out1, N);

  k_gemm2<<<(N + 15) / 16, 256, 0, stream>>>(out1, W2, h2, N);
  k_agg16<<<(N + 15) / 16, 256, 0, stream>>>(h2, off, csrc, cw, dinv, b2, out2, N, 1);
  k_agg16<<<(N + 15) / 16, 256, 0, stream>>>(out2, off, csrc, cw, dinv, nullptr, agg3, N, 0);
  k_gemm3_lsm<<<(N + 3) / 4, 256, 0, stream>>>(agg3, W3, b3, out, N);
}

// Round 3
// 423.319 us; speedup vs baseline: 1.7890x; 1.0889x over previous
//
#include <hip/hip_runtime.h>
#include <hip/hip_bf16.h>
#include <math.h>

typedef __hip_bfloat16 bf16;
typedef __attribute__((ext_vector_type(8))) __bf16 bf16x8;
typedef __attribute__((ext_vector_type(4))) float f32x4;

#define KIN 512
#define F1  256
#define F2  16
#define F3  40

// ---------------- helpers ----------------

__device__ inline unsigned pk_bf2(float a, float b) {
  bf16 x = __float2bfloat16(a), y = __float2bfloat16(b);
  unsigned short ux = *(unsigned short*)&x, uy = *(unsigned short*)&y;
  return (unsigned)ux | ((unsigned)uy << 16);
}
__device__ inline float bfbits(unsigned u16) {
  unsigned v = u16 << 16;
  return *(float*)&v;
}
__device__ inline void async16(const void* g, void* l) {
  __builtin_amdgcn_global_load_lds((const __attribute__((address_space(1))) void*)g,
                                   (__attribute__((address_space(3))) void*)l, 16, 0, 0);
}
__device__ inline void accum8(float* acc, uint4 h, float w) {
  acc[0] = fmaf(w, bfbits(h.x & 0xffff), acc[0]);
  acc[1] = fmaf(w, bfbits(h.x >> 16),    acc[1]);
  acc[2] = fmaf(w, bfbits(h.y & 0xffff), acc[2]);
  acc[3] = fmaf(w, bfbits(h.y >> 16),    acc[3]);
  acc[4] = fmaf(w, bfbits(h.z & 0xffff), acc[4]);
  acc[5] = fmaf(w, bfbits(h.z >> 16),    acc[5]);
  acc[6] = fmaf(w, bfbits(h.w & 0xffff), acc[6]);
  acc[7] = fmaf(w, bfbits(h.w >> 16),    acc[7]);
}

// ---------------- CSR build ----------------

// zero cnt+fill, set int64/int32 flag
__global__ void k_init(int* __restrict__ cnt, int* __restrict__ fill,
                       const int* __restrict__ ei, int* __restrict__ flag, int n) {
  int i = blockIdx.x * 256 + threadIdx.x;
  if (i < n) { cnt[i] = 0; fill[i] = 0; }
  if (i == 0)
    *flag = (ei[1] == 0 && ei[3] == 0 && ei[5] == 0 && ei[7] == 0) ? 1 : 0;
}

__global__ void k_count(const int* __restrict__ ei, const int* __restrict__ flag,
                        int* __restrict__ cnt, int E) {
  int e = blockIdx.x * 256 + threadIdx.x;
  if (e >= E) return;
  int is64 = *flag;
  int d = is64 ? ei[2 * E + 2 * e] : ei[E + e];
  atomicAdd(&cnt[d], 1);
}

// per-1024-chunk scan; also computes dinv
__global__ __launch_bounds__(256) void k_scan1(const int* __restrict__ cnt,
                                               int* __restrict__ off,
                                               int* __restrict__ bsum,
                                               float* __restrict__ dinv, int N) {
  __shared__ int s[256];
  int t = threadIdx.x;
  int base = blockIdx.x * 1024 + t * 4;
  int v0 = (base + 0 < N) ? cnt[base + 0] : 0;
  int v1 = (base + 1 < N) ? cnt[base + 1] : 0;
  int v2 = (base + 2 < N) ? cnt[base + 2] : 0;
  int v3 = (base + 3 < N) ? cnt[base + 3] : 0;
  if (base + 0 < N) dinv[base + 0] = rsqrtf((float)(v0 + 1));
  if (base + 1 < N) dinv[base + 1] = rsqrtf((float)(v1 + 1));
  if (base + 2 < N) dinv[base + 2] = rsqrtf((float)(v2 + 1));
  if (base + 3 < N) dinv[base + 3] = rsqrtf((float)(v3 + 1));
  int tsum = v0 + v1 + v2 + v3;
  s[t] = tsum;
  __syncthreads();
  for (int d = 1; d < 256; d <<= 1) {
    int u = (t >= d) ? s[t - d] : 0;
    __syncthreads();
    s[t] += u;
    __syncthreads();
  }
  int excl = s[t] - tsum;
  int p0 = excl + v0, p1 = p0 + v1, p2 = p1 + v2, p3 = p2 + v3;
  if (base + 0 < N) off[base + 1] = p0;
  if (base + 1 < N) off[base + 2] = p1;
  if (base + 2 < N) off[base + 3] = p2;
  if (base + 3 < N) off[base + 4] = p3;
  if (t == 255) bsum[blockIdx.x] = s[255];
}

__global__ void k_scan2(const int* __restrict__ bsum, int* __restrict__ carry, int nb) {
  int t = threadIdx.x;
  int v = (t < nb) ? bsum[t] : 0;
  int incl = v;
  for (int d = 1; d < 64; d <<= 1) {
    int u = __shfl_up(incl, d, 64);
    if (t >= d) incl += u;
  }
  if (t < nb) carry[t] = incl - v;
}

__global__ __launch_bounds__(256) void k_scan3(int* __restrict__ off,
                                               const int* __restrict__ carry, int N) {
  int t = threadIdx.x;
  int c = carry[blockIdx.x];
  int base = blockIdx.x * 1024 + t * 4;
#pragma unroll
  for (int k = 0; k < 4; ++k)
    if (base + k < N) off[base + k + 1] += c;
  if (blockIdx.x == 0 && t == 0) off[0] = 0;
}

__global__ void k_scatter(const int* __restrict__ ei, const int* __restrict__ flag,
                          const int* __restrict__ off, int* __restrict__ fill,
                          const float* __restrict__ dinv,
                          int* __restrict__ csrc, float* __restrict__ cw, int E) {
  int e = blockIdx.x * 256 + threadIdx.x;
  if (e >= E) return;
  int is64 = *flag;
  int s, d;
  if (is64) { s = ei[2 * e]; d = ei[2 * E + 2 * e]; }
  else      { s = ei[e];     d = ei[E + e]; }
  int pos = off[d] + atomicAdd(&fill[d], 1);
  csrc[pos] = s;
  cw[pos] = dinv[s] * dinv[d];
}

// ---------------- W1 transpose+convert (coalesced LDS tile) ----------------
__global__ __launch_bounds__(256) void k_prep_w1(const float* __restrict__ W,
                                                 unsigned short* __restrict__ Wt) {
  __shared__ float tile[32][33];
  int k0 = blockIdx.x * 32;   // K dim (512)
  int n0 = blockIdx.y * 32;   // N dim (256)
  int t = threadIdx.x;
  int lr = t >> 5, lc = t & 31;
#pragma unroll
  for (int rr = 0; rr < 32; rr += 8)
    tile[lr + rr][lc] = W[(size_t)(k0 + lr + rr) * F1 + n0 + lc];
  __syncthreads();
#pragma unroll
  for (int rr = 0; rr < 32; rr += 8) {
    bf16 v = __float2bfloat16(tile[lc][lr + rr]);
    Wt[(size_t)(n0 + lr + rr) * KIN + k0 + lc] = *(unsigned short*)&v;
  }
}

// ---------------- GEMM1: h1 = bf16(x) @ W1 via MFMA ----------------
// Tile 64(M) x 256(N), BK=32, 4 waves; wave w -> cols [w*64, w*64+64).

__global__ __launch_bounds__(256) void k_gemm1(const float* __restrict__ A,
                                               const unsigned short* __restrict__ Bt,
                                               bf16* __restrict__ C, int M) {
  __shared__ unsigned short As[64 * 32];
  __shared__ unsigned short Bs[256 * 32];
  int t = threadIdx.x;
  int wave = t >> 6, lane = t & 63;
  int row0 = blockIdx.x * 64;

  f32x4 acc[4][4];
#pragma unroll
  for (int i = 0; i < 4; ++i)
#pragma unroll
    for (int j = 0; j < 4; ++j) acc[i][j] = {0.f, 0.f, 0.f, 0.f};

  int arow = t >> 2;
  int achk = t & 3;
  int ar = row0 + arow; if (ar >= M) ar = M - 1;
  const float* ag = A + (size_t)ar * KIN + achk * 8;
  unsigned short* aw = As + arow * 32 + (achk ^ ((arow >> 1) & 3)) * 8;

  int brow_l = lane >> 2;
  int bchk_p = lane & 3;

  for (int k0 = 0; k0 < KIN; k0 += 32) {
    __syncthreads();
    {
      float4 f0 = *(const float4*)(ag + k0);
      float4 f1 = *(const float4*)(ag + k0 + 4);
      uint4 pk;
      pk.x = pk_bf2(f0.x, f0.y); pk.y = pk_bf2(f0.z, f0.w);
      pk.z = pk_bf2(f1.x, f1.y); pk.w = pk_bf2(f1.z, f1.w);
      *(uint4*)aw = pk;
    }
#pragma unroll
    for (int j = 0; j < 4; ++j) {
      int nr = wave * 64 + j * 16;
      int row = nr + brow_l;
      int gchk = bchk_p ^ ((row >> 1) & 3);
      const unsigned short* gp = Bt + (size_t)row * KIN + k0 + gchk * 8;
      async16(gp, Bs + nr * 32);
    }
    __syncthreads();
    int q = lane >> 4, m16 = lane & 15;
    bf16x8 a[4];
#pragma unroll
    for (int i = 0; i < 4; ++i) {
      int m = i * 16 + m16;
      a[i] = *(const bf16x8*)(As + m * 32 + ((q ^ ((m >> 1) & 3)) * 8));
    }
#pragma unroll
    for (int j = 0; j < 4; ++j) {
      int n = wave * 64 + j * 16 + m16;
      bf16x8 b = *(const bf16x8*)(Bs + n * 32 + ((q ^ ((n >> 1) & 3)) * 8));
#pragma unroll
      for (int i = 0; i < 4; ++i)
        acc[i][j] = __builtin_amdgcn_mfma_f32_16x16x32_bf16(a[i], b, acc[i][j], 0, 0, 0);
    }
  }
  int q = lane >> 4, c16 = lane & 15;
#pragma unroll
  for (int i = 0; i < 4; ++i) {
#pragma unroll
    for (int r = 0; r < 4; ++r) {
      int row = row0 + i * 16 + q * 4 + r;
      if (row < M) {
#pragma unroll
        for (int j = 0; j < 4; ++j) {
          int col = wave * 64 + j * 16 + c16;
          C[(size_t)row * F1 + col] = __float2bfloat16(acc[i][j][r]);
        }
      }
    }
  }
}

// ---------------- Aggregation, 256 features (layer 1), edge-unrolled x4 ----
// 8 nodes/block, 32 lanes/node, lane owns 8 features (16B gathers).

__global__ __launch_bounds__(256) void k_agg1(const bf16* __restrict__ H,
                                              const int* __restrict__ off,
                                              const int* __restrict__ csrc,
                                              const float* __restrict__ cw,
                                              const float* __restrict__ dinv,
                                              const float* __restrict__ bias,
                                              bf16* __restrict__ O, int N) {
  int t = threadIdx.x;
  int i = blockIdx.x * 8 + (t >> 5);
  if (i >= N) return;
  int f0 = (t & 31) * 8;
  const unsigned short* Hu = (const unsigned short*)H;
  float di = dinv[i];
  float w0 = di * di;
  float acc[8];
  {
    uint4 h = *(const uint4*)(Hu + (size_t)i * F1 + f0);
    acc[0] = w0 * bfbits(h.x & 0xffff); acc[1] = w0 * bfbits(h.x >> 16);
    acc[2] = w0 * bfbits(h.y & 0xffff); acc[3] = w0 * bfbits(h.y >> 16);
    acc[4] = w0 * bfbits(h.z & 0xffff); acc[5] = w0 * bfbits(h.z >> 16);
    acc[6] = w0 * bfbits(h.w & 0xffff); acc[7] = w0 * bfbits(h.w >> 16);
  }
  int e = off[i], e1 = off[i + 1];
  for (; e + 4 <= e1; e += 4) {
    int s0 = csrc[e + 0], s1 = csrc[e + 1], s2 = csrc[e + 2], s3 = csrc[e + 3];
    float wa = cw[e + 0], wb = cw[e + 1], wc = cw[e + 2], wd = cw[e + 3];
    uint4 g0 = *(const uint4*)(Hu + (size_t)s0 * F1 + f0);
    uint4 g1 = *(const uint4*)(Hu + (size_t)s1 * F1 + f0);
    uint4 g2 = *(const uint4*)(Hu + (size_t)s2 * F1 + f0);
    uint4 g3 = *(const uint4*)(Hu + (size_t)s3 * F1 + f0);
    accum8(acc, g0, wa);
    accum8(acc, g1, wb);
    accum8(acc, g2, wc);
    accum8(acc, g3, wd);
  }
  for (; e < e1; ++e) {
    int s = csrc[e];
    float w = cw[e];
    uint4 g = *(const uint4*)(Hu + (size_t)s * F1 + f0);
    accum8(acc, g, w);
  }
  float4 b0 = *(const float4*)(bias + f0);
  float4 b1 = *(const float4*)(bias + f0 + 4);
  float bb[8] = {b0.x, b0.y, b0.z, b0.w, b1.x, b1.y, b1.z, b1.w};
  uint4 o;
  unsigned* op = (unsigned*)&o;
#pragma unroll
  for (int k = 0; k < 4; ++k) {
    float lo = fmaxf(acc[2 * k] + bb[2 * k], 0.f);
    float hi = fmaxf(acc[2 * k + 1] + bb[2 * k + 1], 0.f);
    op[k] = pk_bf2(lo, hi);
  }
  *(uint4*)((unsigned short*)O + (size_t)i * F1 + f0) = o;
}

// ---------------- GEMM2: h2 = out1 @ W2 (bf16 in, f32 out) ----------------

__global__ __launch_bounds__(256) void k_gemm2(const bf16* __restrict__ A,
                                               const float* __restrict__ W,
                                               float* __restrict__ C, int N) {
  __shared__ float Ws[F1 * F2];
  __shared__ float Ts[16][F1];
  int t = threadIdx.x;
  int r0 = blockIdx.x * 16;
#pragma unroll
  for (int j = 0; j < 16; ++j) Ws[t + 256 * j] = W[t + 256 * j];
  const unsigned short* Au = (const unsigned short*)A;
#pragma unroll
  for (int j = 0; j < 2; ++j) {
    int idx = t + 256 * j;        // 0..511
    int r = idx >> 5;             // 0..15
    int c8 = (idx & 31) * 8;
    int row = r0 + r;
    uint4 g = make_uint4(0, 0, 0, 0);
    if (row < N) g = *(const uint4*)(Au + (size_t)row * F1 + c8);
    float* ts = &Ts[r][c8];
    ts[0] = bfbits(g.x & 0xffff); ts[1] = bfbits(g.x >> 16);
    ts[2] = bfbits(g.y & 0xffff); ts[3] = bfbits(g.y >> 16);
    ts[4] = bfbits(g.z & 0xffff); ts[5] = bfbits(g.z >> 16);
    ts[6] = bfbits(g.w & 0xffff); ts[7] = bfbits(g.w >> 16);
  }
  __syncthreads();
  int r = t >> 4, c = t & 15;
  float acc = 0.f;
  const float4* tv = (const float4*)&Ts[r][0];
#pragma unroll 8
  for (int k4 = 0; k4 < 64; ++k4) {
    float4 a = tv[k4];
    int k = k4 * 4;
    acc = fmaf(a.x, Ws[(k + 0) * 16 + c], acc);
    acc = fmaf(a.y, Ws[(k + 1) * 16 + c], acc);
    acc = fmaf(a.z, Ws[(k + 2) * 16 + c], acc);
    acc = fmaf(a.w, Ws[(k + 3) * 16 + c], acc);
  }
  int row = r0 + r;
  if (row < N) C[(size_t)row * F2 + c] = acc;
}

// ---------------- Aggregation, 16 features, edge-unrolled x4 ----------------

__global__ __launch_bounds__(256) void k_agg16(const float* __restrict__ H,
                                               const int* __restrict__ off,
                                               const int* __restrict__ csrc,
                                               const float* __restrict__ cw,
                                               const float* __restrict__ dinv,
                                               const float* __restrict__ bias,
                                               float* __restrict__ O, int N, int relu) {
  int t = threadIdx.x;
  int i = blockIdx.x * 16 + (t >> 4);
  int f = t & 15;
  if (i >= N) return;
  float di = dinv[i];
  float acc = di * di * H[(size_t)i * F2 + f];
  int e = off[i], e1 = off[i + 1];
  for (; e + 4 <= e1; e += 4) {
    int s0 = csrc[e + 0], s1 = csrc[e + 1], s2 = csrc[e + 2], s3 = csrc[e + 3];
    float wa = cw[e + 0], wb = cw[e + 1], wc = cw[e + 2], wd = cw[e + 3];
    float g0 = H[(size_t)s0 * F2 + f];
    float g1 = H[(size_t)s1 * F2 + f];
    float g2 = H[(size_t)s2 * F2 + f];
    float g3 = H[(size_t)s3 * F2 + f];
    acc = fmaf(wa, g0, acc);
    acc = fmaf(wb, g1, acc);
    acc = fmaf(wc, g2, acc);
    acc = fmaf(wd, g3, acc);
  }
  for (; e < e1; ++e)
    acc = fmaf(cw[e], H[(size_t)csrc[e] * F2 + f], acc);
  if (bias) acc += bias[f];
  if (relu) acc = fmaxf(acc, 0.f);
  O[(size_t)i * F2 + f] = acc;
}

// ---------------- GEMM3 + bias + log_softmax ----------------

__global__ __launch_bounds__(256) void k_gemm3_lsm(const float* __restrict__ A,
                                                   const float* __restrict__ W,
                                                   const float* __restrict__ b,
                                                   float* __restrict__ O, int N) {
  __shared__ float Ws[F2 * F3];
  __shared__ float bs[F3];
  int t = threadIdx.x;
  for (int idx = t; idx < F2 * F3; idx += 256) Ws[idx] = W[idx];
  if (t < F3) bs[t] = b[t];
  __syncthreads();
  int lane = t & 63;
  int wv = t >> 6;
  int row = blockIdx.x * 4 + wv;
  if (row >= N) return;
  const float* ar = A + (size_t)row * F2;
  int c = lane;
  float o = -INFINITY;
  if (c < F3) {
    float acc = bs[c];
#pragma unroll
    for (int k = 0; k < F2; ++k) acc = fmaf(ar[k], Ws[k * F3 + c], acc);
    o = acc;
  }
  float m = o;
  for (int d = 32; d; d >>= 1) m = fmaxf(m, __shfl_xor(m, d, 64));
  float ex = (c < F3) ? expf(o - m) : 0.f;
  float s = ex;
  for (int d = 32; d; d >>= 1) s += __shfl_xor(s, d, 64);
  float lse = m + logf(s);
  if (c < F3) O[(size_t)row * F3 + c] = o - lse;
}

// ---------------- launch ----------------

extern "C" void kernel_launch(void* const* d_in, const int* in_sizes, int n_in,
                              void* d_out, int out_size, void* d_ws, size_t ws_size,
                              hipStream_t stream) {
  const float* x  = (const float*)d_in[0];
  const int*   ei = (const int*)d_in[1];
  const float* W1 = (const float*)d_in[2];
  const float* b1 = (const float*)d_in[3];
  const float* W2 = (const float*)d_in[4];
  const float* b2 = (const float*)d_in[5];
  const float* W3 = (const float*)d_in[6];
  const float* b3 = (const float*)d_in[7];
  float* out = (float*)d_out;

  int N = in_sizes[0] / KIN;
  int E = in_sizes[1] / 2;

  char* p = (char*)d_ws;
  auto take = [&](size_t bytes) {
    char* r = p;
    p += (bytes + 255) & ~(size_t)255;
    return r;
  };
  int*   flag  = (int*)take(4);
  int*   cnt   = (int*)take((size_t)N * 4);
  int*   fill  = (int*)take((size_t)N * 4);
  int*   off   = (int*)take((size_t)(N + 1) * 4);
  float* dinv  = (float*)take((size_t)N * 4);
  int*   bsum  = (int*)take(64 * 4);
  int*   carry = (int*)take(64 * 4);
  int*   csrc  = (int*)take((size_t)E * 4);
  float* cw    = (float*)take((size_t)E * 4);
  unsigned short* w1t = (unsigned short*)take((size_t)KIN * F1 * 2);
  bf16*  h1    = (bf16*)take((size_t)N * F1 * 2);
  bf16*  out1  = (bf16*)take((size_t)N * F1 * 2);
  float* h2    = (float*)take((size_t)N * F2 * 4);
  float* out2  = (float*)take((size_t)N * F2 * 4);
  float* agg3  = (float*)take((size_t)N * F2 * 4);

  int nb  = (N + 255) / 256;
  int ebk = (E + 255) / 256;
  int nsc = (N + 1023) / 1024;

  k_init<<<nb, 256, 0, stream>>>(cnt, fill, ei, flag, N);
  k_count<<<ebk, 256, 0, stream>>>(ei, flag, cnt, E);
  k_scan1<<<nsc, 256, 0, stream>>>(cnt, off, bsum, dinv, N);
  k_scan2<<<1, 64, 0, stream>>>(bsum, carry, nsc);
  k_scan3<<<nsc, 256, 0, stream>>>(off, carry, N);
  k_scatter<<<ebk, 256, 0, stream>>>(ei, flag, off, fill, dinv, csrc, cw, E);

  dim3 gw(KIN / 32, F1 / 32);
  k_prep_w1<<<gw, 256, 0, stream>>>(W1, w1t);
  k_gemm1<<<(N + 63) / 64, 256, 0, stream>>>(x, w1t, h1, N);
  k_agg1<<<(N + 7) / 8, 256, 0, stream>>>(h1, off, csrc, cw, dinv, b1, out1, N);

  k_gemm2<<<(N + 15) / 16, 256, 0, stream>>>(out1, W2, h2, N);
  k_agg16<<<(N + 15) / 16, 256, 0, stream>>>(h2, off, csrc, cw, dinv, b2, out2, N, 1);
  k_agg16<<<(N + 15) / 16, 256, 0, stream>>>(out2, off, csrc, cw, dinv, nullptr, agg3, N, 0);
  k_gemm3_lsm<<<(N + 3) / 4, 256, 0, stream>>>(agg3, W3, b3, out, N);
}